// Round 1
// baseline (166.162 us; speedup 1.0000x reference)
//
#include <hip/hip_runtime.h>

typedef __bf16 bf16x8 __attribute__((ext_vector_type(8)));
typedef float f32x4 __attribute__((ext_vector_type(4)));
typedef unsigned short u16x8 __attribute__((ext_vector_type(8)));

#define B_ 32
#define CC 512
#define HW 192
#define C8_ 64

__device__ inline unsigned short f2bf(float f) {
    unsigned u = __float_as_uint(f);
    unsigned r = (u + 0x7FFFu + ((u >> 16) & 1u)) >> 16;
    return (unsigned short)r;
}

// ---------------- Kernel 1: x [B][C][HW] f32 -> xt [B][HW][C] bf16 ----------
// grid (24, 8), block 256. blockIdx.y picks a 64-wide c-range.
__global__ void k_transpose(const float* __restrict__ x,
                            unsigned short* __restrict__ xt) {
    int gmi = blockIdx.x * 256 + threadIdx.x;   // global (b,m) index, 0..6143
    int b = gmi / HW, m = gmi % HW;
    int c0 = blockIdx.y * 64;
    const float* xb = x + (size_t)b * CC * HW;
    unsigned short* xo = xt + (size_t)(b * HW + m) * CC;
    for (int c8 = 0; c8 < 8; ++c8) {
        u16x8 v;
        #pragma unroll
        for (int i = 0; i < 8; ++i) {
            int c = c0 + c8 * 8 + i;
            v[i] = f2bf(xb[c * HW + m]);        // coalesced across threads (m)
        }
        *(u16x8*)(&xo[c0 + c8 * 8]) = v;
    }
}

// ---------------- Kernel 2: q/k projections (exact f32) ---------------------
// grid (32, 8), block 192. Each block: batch b, 8 q-rows + 8 k-rows.
__global__ void pam_qk(const float* __restrict__ x,
                       const float* __restrict__ Wq, const float* __restrict__ bq,
                       const float* __restrict__ Wk, const float* __restrict__ bk,
                       float* __restrict__ qo, float* __restrict__ ko) {
    int b = blockIdx.x, r0 = blockIdx.y * 8;
    int m = threadIdx.x;                        // 0..191
    float aq[8], ak[8];
    #pragma unroll
    for (int j = 0; j < 8; ++j) { aq[j] = 0.f; ak[j] = 0.f; }
    const float* xb = x + (size_t)b * CC * HW;
    for (int c = 0; c < CC; ++c) {
        float xv = xb[c * HW + m];              // coalesced
        #pragma unroll
        for (int j = 0; j < 8; ++j) {
            aq[j] += Wq[(r0 + j) * CC + c] * xv;  // uniform -> scalar loads
            ak[j] += Wk[(r0 + j) * CC + c] * xv;
        }
    }
    #pragma unroll
    for (int j = 0; j < 8; ++j) {
        qo[((size_t)b * C8_ + r0 + j) * HW + m] = aq[j] + bq[r0 + j];
        ko[((size_t)b * C8_ + r0 + j) * HW + m] = ak[j] + bk[r0 + j];
    }
}

// ---------------- Kernel 3: energy + pos_max --------------------------------
// grid (32, 12), block 192. thread = n; each block does 16 m's for batch b.
__global__ void pam_energy(const float* __restrict__ qo,
                           const float* __restrict__ ko,
                           float* __restrict__ out) {
    int b = blockIdx.x, mg = blockIdx.y;
    int n = threadIdx.x;                        // 0..191
    float kreg[C8_];
    #pragma unroll
    for (int qc = 0; qc < C8_; ++qc)
        kreg[qc] = ko[((size_t)b * C8_ + qc) * HW + n];
    __shared__ float red[3][16];
    int w = n >> 6, lane = n & 63;
    #pragma unroll 1
    for (int mi = 0; mi < 16; ++mi) {
        int m = mg * 16 + mi;
        float e = 0.f;
        #pragma unroll
        for (int qc = 0; qc < C8_; ++qc)
            e += qo[((size_t)b * C8_ + qc) * HW + m] * kreg[qc];  // q uniform
        #pragma unroll
        for (int o = 32; o; o >>= 1) e = fmaxf(e, __shfl_xor(e, o));
        if (lane == 0) red[w][mi] = e;
    }
    __syncthreads();
    if (n < 16) {
        float v = fmaxf(fmaxf(red[0][n], red[1][n]), red[2][n]);
        out[((size_t)B_ * B_ + b) * HW + mg * 16 + n] = v;   // row B of output
    }
}

// ---------------- Kernel 4: Gram tiles + fused row/col max ------------------
// grid 528 (pairs g<=p), block 512 (8 waves, 2x4). Tile 192x192, BK=64.
#define LDK 72   // padded row stride in bf16 elems (144 B, 16B-aligned)

__global__ __launch_bounds__(512) void gram(const unsigned short* __restrict__ xt,
                                            float* __restrict__ out) {
    __shared__ __attribute__((aligned(16))) unsigned short As[HW * LDK];
    __shared__ __attribute__((aligned(16))) unsigned short Bs[HW * LDK];
    __shared__ float colbuf[2][HW];
    __shared__ float rowbuf[4][HW];

    int tid = threadIdx.x;
    // decode pair (g<=p) from triangular index
    int idx = blockIdx.x, g = 0;
    while (idx >= B_ - g) { idx -= B_ - g; ++g; }
    int p = g + idx;

    const unsigned short* xg = xt + (size_t)g * HW * CC;
    const unsigned short* xp = xt + (size_t)p * HW * CC;

    int w = tid >> 6, lane = tid & 63;
    int wr = w >> 2, wc = w & 3;                // 2 x 4 wave grid
    int l15 = lane & 15, lq = lane >> 4;

    f32x4 acc[6][3];
    #pragma unroll
    for (int i = 0; i < 6; ++i)
        #pragma unroll
        for (int j = 0; j < 3; ++j)
            acc[i][j] = (f32x4){0.f, 0.f, 0.f, 0.f};

    for (int kt = 0; kt < 8; ++kt) {
        int k0 = kt * 64;
        __syncthreads();                         // protect LDS overwrite
        #pragma unroll
        for (int i = 0; i < 3; ++i) {            // 3072 chunks / 512 threads / 2 tiles
            int cc = tid + 512 * i;
            int row = cc >> 3, cch = cc & 7;
            int go = row * CC + k0 + cch * 8;
            u16x8 va = *(const u16x8*)(xg + go);
            u16x8 vb = *(const u16x8*)(xp + go);
            *(u16x8*)(&As[row * LDK + cch * 8]) = va;
            *(u16x8*)(&Bs[row * LDK + cch * 8]) = vb;
        }
        __syncthreads();
        #pragma unroll
        for (int kk = 0; kk < 64; kk += 32) {
            int ko = kk + 8 * lq;
            bf16x8 af[6], bfr[3];
            #pragma unroll
            for (int i = 0; i < 6; ++i)
                af[i] = *(const bf16x8*)(&As[(wr * 96 + i * 16 + l15) * LDK + ko]);
            #pragma unroll
            for (int j = 0; j < 3; ++j)
                bfr[j] = *(const bf16x8*)(&Bs[(wc * 48 + j * 16 + l15) * LDK + ko]);
            #pragma unroll
            for (int i = 0; i < 6; ++i)
                #pragma unroll
                for (int j = 0; j < 3; ++j)
                    acc[i][j] = __builtin_amdgcn_mfma_f32_16x16x32_bf16(
                        af[i], bfr[j], acc[i][j], 0, 0, 0);
        }
    }

    // ---- epilogue: col-max (over rows m) -> out[g][p][n]; row-max -> out[p][g][m]
    // D layout (16x16x32): col = lane&15, row = (lane>>4)*4 + reg
    #pragma unroll
    for (int j = 0; j < 3; ++j) {
        float cm = -1e30f;
        #pragma unroll
        for (int i = 0; i < 6; ++i)
            #pragma unroll
            for (int r = 0; r < 4; ++r)
                cm = fmaxf(cm, acc[i][j][r]);
        cm = fmaxf(cm, __shfl_xor(cm, 16));
        cm = fmaxf(cm, __shfl_xor(cm, 32));
        if (lane < 16) colbuf[wr][wc * 48 + j * 16 + l15] = cm;
    }
    #pragma unroll
    for (int i = 0; i < 6; ++i) {
        float rm[4];
        #pragma unroll
        for (int r = 0; r < 4; ++r) rm[r] = -1e30f;
        #pragma unroll
        for (int j = 0; j < 3; ++j)
            #pragma unroll
            for (int r = 0; r < 4; ++r)
                rm[r] = fmaxf(rm[r], acc[i][j][r]);
        #pragma unroll
        for (int msk = 1; msk <= 8; msk <<= 1)
            #pragma unroll
            for (int r = 0; r < 4; ++r)
                rm[r] = fmaxf(rm[r], __shfl_xor(rm[r], msk));
        if (l15 == 0) {
            #pragma unroll
            for (int r = 0; r < 4; ++r)
                rowbuf[wc][wr * 96 + i * 16 + lq * 4 + r] = rm[r];
        }
    }
    __syncthreads();
    if (tid < HW) {
        float cmax = fmaxf(colbuf[0][tid], colbuf[1][tid]);
        out[((size_t)g * B_ + p) * HW + tid] = cmax;
        float rmax = fmaxf(fmaxf(rowbuf[0][tid], rowbuf[1][tid]),
                           fmaxf(rowbuf[2][tid], rowbuf[3][tid]));
        out[((size_t)p * B_ + g) * HW + tid] = rmax;   // same addr if g==p (same value)
    }
}

extern "C" void kernel_launch(void* const* d_in, const int* in_sizes, int n_in,
                              void* d_out, int out_size, void* d_ws, size_t ws_size,
                              hipStream_t stream) {
    (void)in_sizes; (void)n_in; (void)out_size; (void)ws_size;
    const float* x  = (const float*)d_in[0];
    const float* Wq = (const float*)d_in[1];
    const float* bq = (const float*)d_in[2];
    const float* Wk = (const float*)d_in[3];
    const float* bk = (const float*)d_in[4];
    float* out = (float*)d_out;

    char* ws = (char*)d_ws;
    unsigned short* xt = (unsigned short*)ws;                      // 32*192*512*2 = 6291456 B
    float* qbuf = (float*)(ws + 6291456);                          // 32*64*192*4 = 1572864 B
    float* kbuf = (float*)(ws + 6291456 + 1572864);                // 1572864 B

    k_transpose<<<dim3(24, 8), dim3(256), 0, stream>>>(x, xt);
    pam_qk<<<dim3(32, 8), dim3(192), 0, stream>>>(x, Wq, bq, Wk, bk, qbuf, kbuf);
    pam_energy<<<dim3(32, 12), dim3(192), 0, stream>>>(qbuf, kbuf, out);
    gram<<<dim3(528), dim3(512), 0, stream>>>(xt, out);
}

// Round 2
// 81.405 us; speedup vs baseline: 2.0412x; 2.0412x over previous
//
#include <hip/hip_runtime.h>

typedef __bf16 bf16x8 __attribute__((ext_vector_type(8)));
typedef float f32x4 __attribute__((ext_vector_type(4)));
typedef unsigned short u16x8 __attribute__((ext_vector_type(8)));

#define B_ 32
#define CC 512
#define HW 192
#define C8_ 64

__device__ inline unsigned short f2bf(float f) {
    unsigned u = __float_as_uint(f);
    unsigned r = (u + 0x7FFFu + ((u >> 16) & 1u)) >> 16;
    return (unsigned short)r;
}

// ---------------- Kernel 1: x [B][C][HW] f32 -> xt [B][HW][C] bf16 ----------
// grid (24, 8), block 256. blockIdx.y picks a 64-wide c-range.
__global__ void k_transpose(const float* __restrict__ x,
                            unsigned short* __restrict__ xt) {
    int gmi = blockIdx.x * 256 + threadIdx.x;   // global (b,m) index, 0..6143
    int b = gmi / HW, m = gmi % HW;
    int c0 = blockIdx.y * 64;
    const float* xb = x + (size_t)b * CC * HW;
    unsigned short* xo = xt + (size_t)(b * HW + m) * CC;
    for (int c8 = 0; c8 < 8; ++c8) {
        u16x8 v;
        #pragma unroll
        for (int i = 0; i < 8; ++i) {
            int c = c0 + c8 * 8 + i;
            v[i] = f2bf(xb[c * HW + m]);        // coalesced across threads (m)
        }
        *(u16x8*)(&xo[c0 + c8 * 8]) = v;
    }
}

// ---------------- Kernel 2: q/k projections via MFMA ------------------------
// q[b,m,qc] = sum_c xt[b,m,c] * Wq[qc,c] + bq[qc]   (same for k)
// grid (32, 4), block 256 (4 waves). Block: batch b, 48 m-rows, all 64 qc.
// Wave w owns col-fragment qc0 = w*16 for BOTH q and k.
__global__ __launch_bounds__(256) void pam_qk_mfma(
        const unsigned short* __restrict__ xt,
        const float* __restrict__ Wq, const float* __restrict__ bq,
        const float* __restrict__ Wk, const float* __restrict__ bk,
        unsigned short* __restrict__ qo, unsigned short* __restrict__ ko) {
    int b = blockIdx.x, m0 = blockIdx.y * 48;
    int tid = threadIdx.x, w = tid >> 6, lane = tid & 63;
    int l15 = lane & 15, lq = lane >> 4;
    int qc = w * 16 + l15;

    f32x4 accq[3], acck[3];
    #pragma unroll
    for (int i = 0; i < 3; ++i) {
        accq[i] = (f32x4){0.f, 0.f, 0.f, 0.f};
        acck[i] = (f32x4){0.f, 0.f, 0.f, 0.f};
    }

    const unsigned short* xb = xt + ((size_t)b * HW + m0) * CC;
    const float* wqp = Wq + (size_t)qc * CC;
    const float* wkp = Wk + (size_t)qc * CC;

    for (int kt = 0; kt < 16; ++kt) {
        int ko8 = kt * 32 + lq * 8;
        bf16x8 af[3];
        #pragma unroll
        for (int i = 0; i < 3; ++i)
            af[i] = *(const bf16x8*)(xb + (i * 16 + l15) * CC + ko8);
        u16x8 tq, tk;
        #pragma unroll
        for (int e = 0; e < 8; ++e) {
            tq[e] = f2bf(wqp[ko8 + e]);
            tk[e] = f2bf(wkp[ko8 + e]);
        }
        bf16x8 wqf = *(bf16x8*)&tq, wkf = *(bf16x8*)&tk;
        #pragma unroll
        for (int i = 0; i < 3; ++i) {
            accq[i] = __builtin_amdgcn_mfma_f32_16x16x32_bf16(af[i], wqf, accq[i], 0, 0, 0);
            acck[i] = __builtin_amdgcn_mfma_f32_16x16x32_bf16(af[i], wkf, acck[i], 0, 0, 0);
        }
    }

    float bqv = bq[qc], bkv = bk[qc];
    // D layout: col = lane&15 (qc), row = lq*4 + r (m within fragment)
    #pragma unroll
    for (int i = 0; i < 3; ++i) {
        #pragma unroll
        for (int r = 0; r < 4; ++r) {
            int m = m0 + i * 16 + lq * 4 + r;
            qo[((size_t)b * HW + m) * C8_ + qc] = f2bf(accq[i][r] + bqv);
            ko[((size_t)b * HW + m) * C8_ + qc] = f2bf(acck[i][r] + bkv);
        }
    }
}

// ---------------- Kernel 3: energy = q k^T per batch, fused row-max ---------
// grid (32, 4), block 256 (4 waves). Block: batch b, rows m0..m0+47, all 192 n.
// Wave w owns cols n0 = w*48.
__global__ __launch_bounds__(256) void pam_energy_mfma(
        const unsigned short* __restrict__ qo,
        const unsigned short* __restrict__ ko,
        float* __restrict__ out) {
    int b = blockIdx.x, m0 = blockIdx.y * 48;
    int tid = threadIdx.x, w = tid >> 6, lane = tid & 63;
    int l15 = lane & 15, lq = lane >> 4;
    int n0 = w * 48;

    f32x4 acc[3][3];
    #pragma unroll
    for (int i = 0; i < 3; ++i)
        #pragma unroll
        for (int j = 0; j < 3; ++j)
            acc[i][j] = (f32x4){0.f, 0.f, 0.f, 0.f};

    const unsigned short* qb = qo + ((size_t)b * HW + m0) * C8_;
    const unsigned short* kb = ko + ((size_t)b * HW + n0) * C8_;

    #pragma unroll
    for (int kt = 0; kt < 2; ++kt) {
        int ko8 = kt * 32 + lq * 8;
        bf16x8 af[3], bfr[3];
        #pragma unroll
        for (int i = 0; i < 3; ++i)
            af[i] = *(const bf16x8*)(qb + (i * 16 + l15) * C8_ + ko8);
        #pragma unroll
        for (int j = 0; j < 3; ++j)
            bfr[j] = *(const bf16x8*)(kb + (j * 16 + l15) * C8_ + ko8);
        #pragma unroll
        for (int i = 0; i < 3; ++i)
            #pragma unroll
            for (int j = 0; j < 3; ++j)
                acc[i][j] = __builtin_amdgcn_mfma_f32_16x16x32_bf16(af[i], bfr[j], acc[i][j], 0, 0, 0);
    }

    // row max over n (cols): reduce over j-frags + l15 lanes
    __shared__ float red[4][48];
    #pragma unroll
    for (int i = 0; i < 3; ++i) {
        float rm[4];
        #pragma unroll
        for (int r = 0; r < 4; ++r) rm[r] = -1e30f;
        #pragma unroll
        for (int j = 0; j < 3; ++j)
            #pragma unroll
            for (int r = 0; r < 4; ++r)
                rm[r] = fmaxf(rm[r], acc[i][j][r]);
        #pragma unroll
        for (int msk = 1; msk <= 8; msk <<= 1)
            #pragma unroll
            for (int r = 0; r < 4; ++r)
                rm[r] = fmaxf(rm[r], __shfl_xor(rm[r], msk));
        if (l15 == 0) {
            #pragma unroll
            for (int r = 0; r < 4; ++r)
                red[w][i * 16 + lq * 4 + r] = rm[r];
        }
    }
    __syncthreads();
    if (tid < 48) {
        float v = fmaxf(fmaxf(red[0][tid], red[1][tid]),
                        fmaxf(red[2][tid], red[3][tid]));
        out[((size_t)B_ * B_ + b) * HW + m0 + tid] = v;
    }
}

// ---------------- Kernel 4: Gram tiles + fused row/col max ------------------
// grid 528 (pairs g<=p), block 512 (8 waves, 2x4). Tile 192x192, BK=64.
#define LDK 72   // padded row stride in bf16 elems (144 B, 16B-aligned)

__global__ __launch_bounds__(512) void gram(const unsigned short* __restrict__ xt,
                                            float* __restrict__ out) {
    __shared__ __attribute__((aligned(16))) unsigned short As[HW * LDK];
    __shared__ __attribute__((aligned(16))) unsigned short Bs[HW * LDK];
    __shared__ float colbuf[2][HW];
    __shared__ float rowbuf[4][HW];

    int tid = threadIdx.x;
    // decode pair (g<=p) from triangular index
    int idx = blockIdx.x, g = 0;
    while (idx >= B_ - g) { idx -= B_ - g; ++g; }
    int p = g + idx;

    const unsigned short* xg = xt + (size_t)g * HW * CC;
    const unsigned short* xp = xt + (size_t)p * HW * CC;

    int w = tid >> 6, lane = tid & 63;
    int wr = w >> 2, wc = w & 3;                // 2 x 4 wave grid
    int l15 = lane & 15, lq = lane >> 4;

    f32x4 acc[6][3];
    #pragma unroll
    for (int i = 0; i < 6; ++i)
        #pragma unroll
        for (int j = 0; j < 3; ++j)
            acc[i][j] = (f32x4){0.f, 0.f, 0.f, 0.f};

    for (int kt = 0; kt < 8; ++kt) {
        int k0 = kt * 64;
        __syncthreads();                         // protect LDS overwrite
        #pragma unroll
        for (int i = 0; i < 3; ++i) {            // 3072 chunks / 512 threads / 2 tiles
            int cc = tid + 512 * i;
            int row = cc >> 3, cch = cc & 7;
            int go = row * CC + k0 + cch * 8;
            u16x8 va = *(const u16x8*)(xg + go);
            u16x8 vb = *(const u16x8*)(xp + go);
            *(u16x8*)(&As[row * LDK + cch * 8]) = va;
            *(u16x8*)(&Bs[row * LDK + cch * 8]) = vb;
        }
        __syncthreads();
        #pragma unroll
        for (int kk = 0; kk < 64; kk += 32) {
            int ko = kk + 8 * lq;
            bf16x8 af[6], bfr[3];
            #pragma unroll
            for (int i = 0; i < 6; ++i)
                af[i] = *(const bf16x8*)(&As[(wr * 96 + i * 16 + l15) * LDK + ko]);
            #pragma unroll
            for (int j = 0; j < 3; ++j)
                bfr[j] = *(const bf16x8*)(&Bs[(wc * 48 + j * 16 + l15) * LDK + ko]);
            #pragma unroll
            for (int i = 0; i < 6; ++i)
                #pragma unroll
                for (int j = 0; j < 3; ++j)
                    acc[i][j] = __builtin_amdgcn_mfma_f32_16x16x32_bf16(
                        af[i], bfr[j], acc[i][j], 0, 0, 0);
        }
    }

    // ---- epilogue: col-max (over rows m) -> out[g][p][n]; row-max -> out[p][g][m]
    // D layout (16x16x32): col = lane&15, row = (lane>>4)*4 + reg
    #pragma unroll
    for (int j = 0; j < 3; ++j) {
        float cm = -1e30f;
        #pragma unroll
        for (int i = 0; i < 6; ++i)
            #pragma unroll
            for (int r = 0; r < 4; ++r)
                cm = fmaxf(cm, acc[i][j][r]);
        cm = fmaxf(cm, __shfl_xor(cm, 16));
        cm = fmaxf(cm, __shfl_xor(cm, 32));
        if (lane < 16) colbuf[wr][wc * 48 + j * 16 + l15] = cm;
    }
    #pragma unroll
    for (int i = 0; i < 6; ++i) {
        float rm[4];
        #pragma unroll
        for (int r = 0; r < 4; ++r) rm[r] = -1e30f;
        #pragma unroll
        for (int j = 0; j < 3; ++j)
            #pragma unroll
            for (int r = 0; r < 4; ++r)
                rm[r] = fmaxf(rm[r], acc[i][j][r]);
        #pragma unroll
        for (int msk = 1; msk <= 8; msk <<= 1)
            #pragma unroll
            for (int r = 0; r < 4; ++r)
                rm[r] = fmaxf(rm[r], __shfl_xor(rm[r], msk));
        if (l15 == 0) {
            #pragma unroll
            for (int r = 0; r < 4; ++r)
                rowbuf[wc][wr * 96 + i * 16 + lq * 4 + r] = rm[r];
        }
    }
    __syncthreads();
    if (tid < HW) {
        float cmax = fmaxf(colbuf[0][tid], colbuf[1][tid]);
        out[((size_t)g * B_ + p) * HW + tid] = cmax;
        float rmax = fmaxf(fmaxf(rowbuf[0][tid], rowbuf[1][tid]),
                           fmaxf(rowbuf[2][tid], rowbuf[3][tid]));
        out[((size_t)p * B_ + g) * HW + tid] = rmax;   // same addr if g==p (same value)
    }
}

extern "C" void kernel_launch(void* const* d_in, const int* in_sizes, int n_in,
                              void* d_out, int out_size, void* d_ws, size_t ws_size,
                              hipStream_t stream) {
    (void)in_sizes; (void)n_in; (void)out_size; (void)ws_size;
    const float* x  = (const float*)d_in[0];
    const float* Wq = (const float*)d_in[1];
    const float* bq = (const float*)d_in[2];
    const float* Wk = (const float*)d_in[3];
    const float* bk = (const float*)d_in[4];
    float* out = (float*)d_out;

    char* ws = (char*)d_ws;
    unsigned short* xt = (unsigned short*)ws;                      // 32*192*512*2 = 6291456 B
    unsigned short* qbuf = (unsigned short*)(ws + 6291456);        // 32*192*64*2 = 786432 B
    unsigned short* kbuf = (unsigned short*)(ws + 6291456 + 786432);

    k_transpose<<<dim3(24, 8), dim3(256), 0, stream>>>(x, xt);
    pam_qk_mfma<<<dim3(32, 4), dim3(256), 0, stream>>>(xt, Wq, bq, Wk, bk, qbuf, kbuf);
    pam_energy_mfma<<<dim3(32, 4), dim3(256), 0, stream>>>(qbuf, kbuf, out);
    gram<<<dim3(528), dim3(512), 0, stream>>>(xt, out);
}

// Round 3
// 64.998 us; speedup vs baseline: 2.5564x; 1.2524x over previous
//
#include <hip/hip_runtime.h>

typedef __bf16 bf16x8 __attribute__((ext_vector_type(8)));
typedef float f32x4 __attribute__((ext_vector_type(4)));
typedef unsigned short u16x8 __attribute__((ext_vector_type(8)));

#define B_ 32
#define CC 512
#define HW 192
#define C8_ 64

__device__ inline unsigned short f2bf(float f) {
    unsigned u = __float_as_uint(f);
    unsigned r = (u + 0x7FFFu + ((u >> 16) & 1u)) >> 16;
    return (unsigned short)r;
}

__device__ inline void gload16(const void* g, void* l) {
    __builtin_amdgcn_global_load_lds(
        (const __attribute__((address_space(1))) unsigned*)g,
        (__attribute__((address_space(3))) unsigned*)l,
        16, 0, 0);
}

// ---------------- Kernel 1: x [B][C][HW] f32 -> xt [B][HW][C] bf16 ----------
__global__ void k_transpose(const float* __restrict__ x,
                            unsigned short* __restrict__ xt) {
    int gmi = blockIdx.x * 256 + threadIdx.x;   // global (b,m) index, 0..6143
    int b = gmi / HW, m = gmi % HW;
    int c0 = blockIdx.y * 64;
    const float* xb = x + (size_t)b * CC * HW;
    unsigned short* xo = xt + (size_t)(b * HW + m) * CC;
    for (int c8 = 0; c8 < 8; ++c8) {
        u16x8 v;
        #pragma unroll
        for (int i = 0; i < 8; ++i) {
            int c = c0 + c8 * 8 + i;
            v[i] = f2bf(xb[c * HW + m]);        // coalesced across threads (m)
        }
        *(u16x8*)(&xo[c0 + c8 * 8]) = v;
    }
}

// ---------------- Kernel 2: q/k projections via MFMA ------------------------
__global__ __launch_bounds__(256) void pam_qk_mfma(
        const unsigned short* __restrict__ xt,
        const float* __restrict__ Wq, const float* __restrict__ bq,
        const float* __restrict__ Wk, const float* __restrict__ bk,
        unsigned short* __restrict__ qo, unsigned short* __restrict__ ko) {
    int b = blockIdx.x, m0 = blockIdx.y * 48;
    int tid = threadIdx.x, w = tid >> 6, lane = tid & 63;
    int l15 = lane & 15, lq = lane >> 4;
    int qc = w * 16 + l15;

    f32x4 accq[3], acck[3];
    #pragma unroll
    for (int i = 0; i < 3; ++i) {
        accq[i] = (f32x4){0.f, 0.f, 0.f, 0.f};
        acck[i] = (f32x4){0.f, 0.f, 0.f, 0.f};
    }

    const unsigned short* xb = xt + ((size_t)b * HW + m0) * CC;
    const float* wqp = Wq + (size_t)qc * CC;
    const float* wkp = Wk + (size_t)qc * CC;

    for (int kt = 0; kt < 16; ++kt) {
        int ko8 = kt * 32 + lq * 8;
        bf16x8 af[3];
        #pragma unroll
        for (int i = 0; i < 3; ++i)
            af[i] = *(const bf16x8*)(xb + (i * 16 + l15) * CC + ko8);
        u16x8 tq, tk;
        #pragma unroll
        for (int e = 0; e < 8; ++e) {
            tq[e] = f2bf(wqp[ko8 + e]);
            tk[e] = f2bf(wkp[ko8 + e]);
        }
        bf16x8 wqf = *(bf16x8*)&tq, wkf = *(bf16x8*)&tk;
        #pragma unroll
        for (int i = 0; i < 3; ++i) {
            accq[i] = __builtin_amdgcn_mfma_f32_16x16x32_bf16(af[i], wqf, accq[i], 0, 0, 0);
            acck[i] = __builtin_amdgcn_mfma_f32_16x16x32_bf16(af[i], wkf, acck[i], 0, 0, 0);
        }
    }

    float bqv = bq[qc], bkv = bk[qc];
    #pragma unroll
    for (int i = 0; i < 3; ++i) {
        #pragma unroll
        for (int r = 0; r < 4; ++r) {
            int m = m0 + i * 16 + lq * 4 + r;
            qo[((size_t)b * HW + m) * C8_ + qc] = f2bf(accq[i][r] + bqv);
            ko[((size_t)b * HW + m) * C8_ + qc] = f2bf(acck[i][r] + bkv);
        }
    }
}

// ---------------- Kernel 3: energy = q k^T per batch, fused row-max ---------
__global__ __launch_bounds__(256) void pam_energy_mfma(
        const unsigned short* __restrict__ qo,
        const unsigned short* __restrict__ ko,
        float* __restrict__ out) {
    int b = blockIdx.x, m0 = blockIdx.y * 48;
    int tid = threadIdx.x, w = tid >> 6, lane = tid & 63;
    int l15 = lane & 15, lq = lane >> 4;
    int n0 = w * 48;

    f32x4 acc[3][3];
    #pragma unroll
    for (int i = 0; i < 3; ++i)
        #pragma unroll
        for (int j = 0; j < 3; ++j)
            acc[i][j] = (f32x4){0.f, 0.f, 0.f, 0.f};

    const unsigned short* qb = qo + ((size_t)b * HW + m0) * C8_;
    const unsigned short* kb = ko + ((size_t)b * HW + n0) * C8_;

    #pragma unroll
    for (int kt = 0; kt < 2; ++kt) {
        int ko8 = kt * 32 + lq * 8;
        bf16x8 af[3], bfr[3];
        #pragma unroll
        for (int i = 0; i < 3; ++i)
            af[i] = *(const bf16x8*)(qb + (i * 16 + l15) * C8_ + ko8);
        #pragma unroll
        for (int j = 0; j < 3; ++j)
            bfr[j] = *(const bf16x8*)(kb + (j * 16 + l15) * C8_ + ko8);
        #pragma unroll
        for (int i = 0; i < 3; ++i)
            #pragma unroll
            for (int j = 0; j < 3; ++j)
                acc[i][j] = __builtin_amdgcn_mfma_f32_16x16x32_bf16(af[i], bfr[j], acc[i][j], 0, 0, 0);
    }

    __shared__ float red[4][48];
    #pragma unroll
    for (int i = 0; i < 3; ++i) {
        float rm[4];
        #pragma unroll
        for (int r = 0; r < 4; ++r) rm[r] = -1e30f;
        #pragma unroll
        for (int j = 0; j < 3; ++j)
            #pragma unroll
            for (int r = 0; r < 4; ++r)
                rm[r] = fmaxf(rm[r], acc[i][j][r]);
        #pragma unroll
        for (int msk = 1; msk <= 8; msk <<= 1)
            #pragma unroll
            for (int r = 0; r < 4; ++r)
                rm[r] = fmaxf(rm[r], __shfl_xor(rm[r], msk));
        if (l15 == 0) {
            #pragma unroll
            for (int r = 0; r < 4; ++r)
                red[w][i * 16 + lq * 4 + r] = rm[r];
        }
    }
    __syncthreads();
    if (tid < 48) {
        float v = fmaxf(fmaxf(red[0][tid], red[1][tid]),
                        fmaxf(red[2][tid], red[3][tid]));
        out[((size_t)B_ * B_ + b) * HW + m0 + tid] = v;
    }
}

// ---------------- Kernel 4: Gram tiles + fused row/col max ------------------
// grid 528 (pairs g<=p), block 512 (8 waves, 2x4). Tile 192x192, BK=64,
// double-buffered LDS staged via global_load_lds (linear layout) with
// XOR slot-swizzle (slot ^= row&7) applied to read addr + inverse on the
// per-lane global source. LDS: 2*(192*64)*2B*2 tiles = 98304 B + 4608 B bufs.
#define TILE_B 24576              // bytes per (192x64 bf16) tile
#define SMEM_BYTES 102912

__global__ __launch_bounds__(512) void gram(const unsigned short* __restrict__ xt,
                                            float* __restrict__ out) {
    extern __shared__ char smem[];
    float* colbuf = (float*)(smem + 2 * TILE_B * 2);           // [2][192]
    float* rowbuf = (float*)(smem + 2 * TILE_B * 2 + 1536);    // [4][192]

    int tid = threadIdx.x;
    // XCD-aware bijective swizzle (528 % 8 == 0): 66 consecutive tri-indices per XCD
    int bid = (blockIdx.x & 7) * 66 + (blockIdx.x >> 3);
    int idx = bid, g = 0;
    while (idx >= B_ - g) { idx -= B_ - g; ++g; }
    int p = g + idx;

    const unsigned short* xg = xt + (size_t)g * HW * CC;
    const unsigned short* xp = xt + (size_t)p * HW * CC;

    int w = tid >> 6, lane = tid & 63;
    int wr = w >> 2, wc = w & 3;                // 2 x 4 wave grid
    int l15 = lane & 15, lq = lane >> 4;

    // staging: wave w stages rows [24w, 24w+24) of both tiles, 3 chunks of 8 rows.
    // lane l -> row = base + (l>>3), phys slot = l&7 holds k-elems ((l&7)^(l>>3))*8..+8
    int l8 = lane >> 3, s8 = lane & 7;
    const unsigned short* agp = xg + (size_t)(24 * w + l8) * CC + ((s8 ^ l8) << 3);
    const unsigned short* bgp = xp + (size_t)(24 * w + l8) * CC + ((s8 ^ l8) << 3);
    unsigned ldsw = (unsigned)(24 * w) * 128;   // byte offset of wave's rows in tile

    // read offsets (byte, within tile): row*128 + ((lq ^ (row&7))<<4); kk=32 -> ^64
    unsigned aoff[6], boff[3];
    #pragma unroll
    for (int i = 0; i < 6; ++i) {
        int row = wr * 96 + i * 16 + l15;
        aoff[i] = row * 128 + ((unsigned)(lq ^ (row & 7)) << 4);
    }
    #pragma unroll
    for (int j = 0; j < 3; ++j) {
        int row = wc * 48 + j * 16 + l15;
        boff[j] = row * 128 + ((unsigned)(lq ^ (row & 7)) << 4);
    }

    f32x4 acc[6][3];
    #pragma unroll
    for (int i = 0; i < 6; ++i)
        #pragma unroll
        for (int j = 0; j < 3; ++j)
            acc[i][j] = (f32x4){0.f, 0.f, 0.f, 0.f};

    #define STAGE(buf, k0)                                                     \
        {                                                                      \
            char* ab = smem + (buf) * TILE_B + ldsw;                           \
            char* bb = smem + 2 * TILE_B + (buf) * TILE_B + ldsw;              \
            _Pragma("unroll")                                                  \
            for (int ci = 0; ci < 3; ++ci) {                                   \
                gload16(agp + (k0) + ci * 8 * CC, ab + ci * 1024);             \
                gload16(bgp + (k0) + ci * 8 * CC, bb + ci * 1024);             \
            }                                                                  \
        }

    STAGE(0, 0);
    __syncthreads();                             // vmcnt(0) drain + barrier

    for (int kt = 0; kt < 8; ++kt) {
        int cur = kt & 1;
        if (kt < 7) STAGE(cur ^ 1, (kt + 1) * 64);
        const char* Ab = smem + cur * TILE_B;
        const char* Bb = smem + 2 * TILE_B + cur * TILE_B;
        #pragma unroll
        for (int kx = 0; kx < 128; kx += 64) {   // kk = 0, 32  (byte XOR 0/64)
            bf16x8 af[6], bfr[3];
            #pragma unroll
            for (int i = 0; i < 6; ++i)
                af[i] = *(const bf16x8*)(Ab + (aoff[i] ^ kx));
            #pragma unroll
            for (int j = 0; j < 3; ++j)
                bfr[j] = *(const bf16x8*)(Bb + (boff[j] ^ kx));
            #pragma unroll
            for (int i = 0; i < 6; ++i)
                #pragma unroll
                for (int j = 0; j < 3; ++j)
                    acc[i][j] = __builtin_amdgcn_mfma_f32_16x16x32_bf16(
                        af[i], bfr[j], acc[i][j], 0, 0, 0);
        }
        __syncthreads();                         // next buf landed + reads done
    }

    // ---- epilogue: col-max (over rows m) -> out[g][p][n]; row-max -> out[p][g][m]
    #pragma unroll
    for (int j = 0; j < 3; ++j) {
        float cm = -1e30f;
        #pragma unroll
        for (int i = 0; i < 6; ++i)
            #pragma unroll
            for (int r = 0; r < 4; ++r)
                cm = fmaxf(cm, acc[i][j][r]);
        cm = fmaxf(cm, __shfl_xor(cm, 16));
        cm = fmaxf(cm, __shfl_xor(cm, 32));
        if (lane < 16) colbuf[wr * HW + wc * 48 + j * 16 + l15] = cm;
    }
    #pragma unroll
    for (int i = 0; i < 6; ++i) {
        float rm[4];
        #pragma unroll
        for (int r = 0; r < 4; ++r) rm[r] = -1e30f;
        #pragma unroll
        for (int j = 0; j < 3; ++j)
            #pragma unroll
            for (int r = 0; r < 4; ++r)
                rm[r] = fmaxf(rm[r], acc[i][j][r]);
        #pragma unroll
        for (int msk = 1; msk <= 8; msk <<= 1)
            #pragma unroll
            for (int r = 0; r < 4; ++r)
                rm[r] = fmaxf(rm[r], __shfl_xor(rm[r], msk));
        if (l15 == 0) {
            #pragma unroll
            for (int r = 0; r < 4; ++r)
                rowbuf[wc * HW + wr * 96 + i * 16 + lq * 4 + r] = rm[r];
        }
    }
    __syncthreads();
    if (tid < HW) {
        float cmax = fmaxf(colbuf[tid], colbuf[HW + tid]);
        out[((size_t)g * B_ + p) * HW + tid] = cmax;
        float rmax = fmaxf(fmaxf(rowbuf[tid], rowbuf[HW + tid]),
                           fmaxf(rowbuf[2 * HW + tid], rowbuf[3 * HW + tid]));
        out[((size_t)p * B_ + g) * HW + tid] = rmax;   // same addr if g==p (same value)
    }
}

extern "C" void kernel_launch(void* const* d_in, const int* in_sizes, int n_in,
                              void* d_out, int out_size, void* d_ws, size_t ws_size,
                              hipStream_t stream) {
    (void)in_sizes; (void)n_in; (void)out_size; (void)ws_size;
    const float* x  = (const float*)d_in[0];
    const float* Wq = (const float*)d_in[1];
    const float* bq = (const float*)d_in[2];
    const float* Wk = (const float*)d_in[3];
    const float* bk = (const float*)d_in[4];
    float* out = (float*)d_out;

    char* ws = (char*)d_ws;
    unsigned short* xt = (unsigned short*)ws;                      // 6291456 B
    unsigned short* qbuf = (unsigned short*)(ws + 6291456);        // 786432 B
    unsigned short* kbuf = (unsigned short*)(ws + 6291456 + 786432);

    // allow >64KB dynamic LDS for gram (idempotent, host-side, capture-safe)
    hipFuncSetAttribute((const void*)gram,
                        hipFuncAttributeMaxDynamicSharedMemorySize, SMEM_BYTES);

    k_transpose<<<dim3(24, 8), dim3(256), 0, stream>>>(x, xt);
    pam_qk_mfma<<<dim3(32, 4), dim3(256), 0, stream>>>(xt, Wq, bq, Wk, bk, qbuf, kbuf);
    pam_energy_mfma<<<dim3(32, 4), dim3(256), 0, stream>>>(qbuf, kbuf, out);
    gram<<<dim3(528), dim3(512), SMEM_BYTES, stream>>>(xt, out);
}